// Round 1
// baseline (643.547 us; speedup 1.0000x reference)
//
#include <hip/hip_runtime.h>
#include <math.h>

// Problem constants
#define BB   32
#define CC   512
#define HWN  1024   // H*W
#define MM   77
#define TXT  768
#define NH   8
#define HD   64
#define SCALEF 0.125f   // 1/sqrt(64)

// ---------------------------------------------------------------------------
// Q = x_flat @ Wq^T + bq      x: [B, C, N] -> x_flat[b,n,c] = x[b,c,n]
// Q[b,n,co] = sum_c x[b,c,n] * Wq[co,c] + bq[co]
// 64x64 output tile per block, K-step 16, 256 threads (16x16, 4x4 each).
// ---------------------------------------------------------------------------
__global__ __launch_bounds__(256) void qgemm_kernel(
    const float* __restrict__ x, const float* __restrict__ Wq,
    const float* __restrict__ bq, float* __restrict__ Q)
{
    const int nt = blockIdx.x;      // 0..15  (n tile)
    const int ct = blockIdx.y;      // 0..7   (co tile)
    const int b  = blockIdx.z;      // 0..31
    const int n0 = nt * 64, co0 = ct * 64;

    __shared__ float As[16][64];    // [c][n]
    __shared__ float Bs[16][68];    // [c][co]  (padded pitch, 16B-aligned rows)

    const int t  = threadIdx.x;
    const int tx = t & 15;          // co dir
    const int ty = t >> 4;          // n dir

    float acc[4][4] = {};

    const float* xb = x + (size_t)b * CC * HWN;

    for (int k0 = 0; k0 < CC; k0 += 16) {
        #pragma unroll
        for (int l = 0; l < 4; ++l) {
            const int c = l * 4 + (t >> 6);
            As[c][t & 63] = xb[(size_t)(k0 + c) * HWN + n0 + (t & 63)];
        }
        {
            const int co = t >> 2, c4 = (t & 3) * 4;
            const float4 w = *(const float4*)&Wq[(size_t)(co0 + co) * CC + k0 + c4];
            Bs[c4 + 0][co] = w.x; Bs[c4 + 1][co] = w.y;
            Bs[c4 + 2][co] = w.z; Bs[c4 + 3][co] = w.w;
        }
        __syncthreads();
        #pragma unroll
        for (int cc = 0; cc < 16; ++cc) {
            const float4 a4 = *(const float4*)&As[cc][ty * 4];
            const float4 b4 = *(const float4*)&Bs[cc][tx * 4];
            const float av[4] = {a4.x, a4.y, a4.z, a4.w};
            const float bv[4] = {b4.x, b4.y, b4.z, b4.w};
            #pragma unroll
            for (int i = 0; i < 4; ++i)
                #pragma unroll
                for (int j = 0; j < 4; ++j)
                    acc[i][j] = fmaf(av[i], bv[j], acc[i][j]);
        }
        __syncthreads();
    }

    const float4 bias = *(const float4*)&bq[co0 + tx * 4];
    #pragma unroll
    for (int i = 0; i < 4; ++i) {
        const int n = n0 + ty * 4 + i;
        float4 st;
        st.x = acc[i][0] + bias.x; st.y = acc[i][1] + bias.y;
        st.z = acc[i][2] + bias.z; st.w = acc[i][3] + bias.w;
        *(float4*)&Q[((size_t)b * HWN + n) * CC + co0 + tx * 4] = st;
    }
}

// ---------------------------------------------------------------------------
// K = text_emb @ Wk^T + bk ; V = text_emb @ Wv^T + bv   (fused)
// ---------------------------------------------------------------------------
__global__ __launch_bounds__(256) void kvgemm_kernel(
    const float* __restrict__ te,
    const float* __restrict__ Wk, const float* __restrict__ bk,
    const float* __restrict__ Wv, const float* __restrict__ bv,
    float* __restrict__ K, float* __restrict__ V)
{
    const int ct = blockIdx.x;      // 0..7
    const int b  = blockIdx.y;      // 0..31
    const int co0 = ct * 64;

    __shared__ float As[16][80];    // [c][m], m padded 77->80
    __shared__ float Bk[16][68];    // [c][co]
    __shared__ float Bv[16][68];

    const int t  = threadIdx.x;
    const int tx = t & 15;
    const int ty = t >> 4;

    float ak[5][4] = {};
    float av[5][4] = {};

    const float* teb = te + (size_t)b * MM * TXT;

    for (int k0 = 0; k0 < TXT; k0 += 16) {
        {
            const int c4 = (t & 3) * 4;
            const int m  = t >> 2;                 // 0..63
            const float4 v = *(const float4*)&teb[(size_t)m * TXT + k0 + c4];
            As[c4 + 0][m] = v.x; As[c4 + 1][m] = v.y;
            As[c4 + 2][m] = v.z; As[c4 + 3][m] = v.w;
            if (t < 64) {
                const int m2 = 64 + (t >> 2);      // 64..79
                float4 v2 = make_float4(0.f, 0.f, 0.f, 0.f);
                if (m2 < MM) v2 = *(const float4*)&teb[(size_t)m2 * TXT + k0 + c4];
                As[c4 + 0][m2] = v2.x; As[c4 + 1][m2] = v2.y;
                As[c4 + 2][m2] = v2.z; As[c4 + 3][m2] = v2.w;
            }
        }
        {
            const int co = t >> 2, c4 = (t & 3) * 4;
            const float4 wk = *(const float4*)&Wk[(size_t)(co0 + co) * TXT + k0 + c4];
            Bk[c4 + 0][co] = wk.x; Bk[c4 + 1][co] = wk.y;
            Bk[c4 + 2][co] = wk.z; Bk[c4 + 3][co] = wk.w;
            const float4 wv = *(const float4*)&Wv[(size_t)(co0 + co) * TXT + k0 + c4];
            Bv[c4 + 0][co] = wv.x; Bv[c4 + 1][co] = wv.y;
            Bv[c4 + 2][co] = wv.z; Bv[c4 + 3][co] = wv.w;
        }
        __syncthreads();
        #pragma unroll
        for (int cc = 0; cc < 16; ++cc) {
            const float4 k4 = *(const float4*)&Bk[cc][tx * 4];
            const float4 v4 = *(const float4*)&Bv[cc][tx * 4];
            #pragma unroll
            for (int i = 0; i < 5; ++i) {
                const float a = As[cc][ty + 16 * i];
                ak[i][0] = fmaf(a, k4.x, ak[i][0]);
                ak[i][1] = fmaf(a, k4.y, ak[i][1]);
                ak[i][2] = fmaf(a, k4.z, ak[i][2]);
                ak[i][3] = fmaf(a, k4.w, ak[i][3]);
                av[i][0] = fmaf(a, v4.x, av[i][0]);
                av[i][1] = fmaf(a, v4.y, av[i][1]);
                av[i][2] = fmaf(a, v4.z, av[i][2]);
                av[i][3] = fmaf(a, v4.w, av[i][3]);
            }
        }
        __syncthreads();
    }

    const float4 bk4 = *(const float4*)&bk[co0 + tx * 4];
    const float4 bv4 = *(const float4*)&bv[co0 + tx * 4];
    #pragma unroll
    for (int i = 0; i < 5; ++i) {
        const int m = ty + 16 * i;
        if (m < MM) {
            float4 sk, sv;
            sk.x = ak[i][0] + bk4.x; sk.y = ak[i][1] + bk4.y;
            sk.z = ak[i][2] + bk4.z; sk.w = ak[i][3] + bk4.w;
            sv.x = av[i][0] + bv4.x; sv.y = av[i][1] + bv4.y;
            sv.z = av[i][2] + bv4.z; sv.w = av[i][3] + bv4.w;
            *(float4*)&K[((size_t)b * MM + m) * CC + co0 + tx * 4] = sk;
            *(float4*)&V[((size_t)b * MM + m) * CC + co0 + tx * 4] = sv;
        }
    }
}

// ---------------------------------------------------------------------------
// Attention: per (b, h, 64-row n tile).
// ---------------------------------------------------------------------------
__global__ __launch_bounds__(256) void attn_kernel(
    const float* __restrict__ Q, const float* __restrict__ K,
    const float* __restrict__ V, const int* __restrict__ amask,
    float* __restrict__ out)
{
    const int nt = blockIdx.x;      // 0..15
    const int h  = blockIdx.y;      // 0..7
    const int b  = blockIdx.z;      // 0..31
    const int n0 = nt * 64;

    __shared__ float Ks[MM][68];
    __shared__ float Vs[MM][68];
    __shared__ float Ps[64][MM];
    __shared__ int   msk[MM];

    const int t = threadIdx.x;

    for (int idx = t; idx < MM * 16; idx += 256) {
        const int m = idx >> 4, k4 = (idx & 15) * 4;
        const float4 kv = *(const float4*)&K[((size_t)b * MM + m) * CC + h * HD + k4];
        *(float4*)&Ks[m][k4] = kv;
        const float4 vv = *(const float4*)&V[((size_t)b * MM + m) * CC + h * HD + k4];
        *(float4*)&Vs[m][k4] = vv;
    }
    if (t < MM) msk[t] = amask[b * MM + t];

    const int r = t >> 2;           // 0..63
    const int q = t & 3;            // k-chunk
    const float* qrow = Q + ((size_t)b * HWN + n0 + r) * CC + h * HD + q * 16;
    const float4 q0 = *(const float4*)&qrow[0];
    const float4 q1 = *(const float4*)&qrow[4];
    const float4 q2 = *(const float4*)&qrow[8];
    const float4 q3 = *(const float4*)&qrow[12];

    __syncthreads();

    float s[20];
    const int cnt = (80 - q) >> 2;  // 20,19,19,19
    for (int m = 0; m < MM; ++m) {
        const float4 k0v = *(const float4*)&Ks[m][q * 16 + 0];
        const float4 k1v = *(const float4*)&Ks[m][q * 16 + 4];
        const float4 k2v = *(const float4*)&Ks[m][q * 16 + 8];
        const float4 k3v = *(const float4*)&Ks[m][q * 16 + 12];
        float p = q0.x * k0v.x;
        p = fmaf(q0.y, k0v.y, p); p = fmaf(q0.z, k0v.z, p); p = fmaf(q0.w, k0v.w, p);
        p = fmaf(q1.x, k1v.x, p); p = fmaf(q1.y, k1v.y, p);
        p = fmaf(q1.z, k1v.z, p); p = fmaf(q1.w, k1v.w, p);
        p = fmaf(q2.x, k2v.x, p); p = fmaf(q2.y, k2v.y, p);
        p = fmaf(q2.z, k2v.z, p); p = fmaf(q2.w, k2v.w, p);
        p = fmaf(q3.x, k3v.x, p); p = fmaf(q3.y, k3v.y, p);
        p = fmaf(q3.z, k3v.z, p); p = fmaf(q3.w, k3v.w, p);
        p += __shfl_xor(p, 1, 64);
        p += __shfl_xor(p, 2, 64);
        if ((m & 3) == q) s[m >> 2] = p * SCALEF;
    }

    float mx = -INFINITY;
    #pragma unroll
    for (int i = 0; i < 20; ++i) {
        if (i < cnt) {
            const int m = 4 * i + q;
            if (msk[m] == 0) s[i] = -INFINITY;
            mx = fmaxf(mx, s[i]);
        }
    }
    mx = fmaxf(mx, __shfl_xor(mx, 1, 64));
    mx = fmaxf(mx, __shfl_xor(mx, 2, 64));
    float sum = 0.f;
    #pragma unroll
    for (int i = 0; i < 20; ++i) {
        if (i < cnt) {
            const float e = __expf(s[i] - mx);
            s[i] = e;
            sum += e;
        }
    }
    sum += __shfl_xor(sum, 1, 64);
    sum += __shfl_xor(sum, 2, 64);
    const float inv = 1.0f / sum;
    #pragma unroll
    for (int i = 0; i < 20; ++i)
        if (i < cnt) Ps[r][4 * i + q] = s[i] * inv;

    __syncthreads();

    const int w     = t >> 6;
    const int lane  = t & 63;
    const int dbase = w * 16;
    float4 a0 = make_float4(0, 0, 0, 0), a1 = a0, a2 = a0, a3 = a0;
    for (int m = 0; m < MM; ++m) {
        const float p = Ps[lane][m];
        const float4 v0 = *(const float4*)&Vs[m][dbase + 0];
        const float4 v1 = *(const float4*)&Vs[m][dbase + 4];
        const float4 v2 = *(const float4*)&Vs[m][dbase + 8];
        const float4 v3 = *(const float4*)&Vs[m][dbase + 12];
        a0.x = fmaf(p, v0.x, a0.x); a0.y = fmaf(p, v0.y, a0.y);
        a0.z = fmaf(p, v0.z, a0.z); a0.w = fmaf(p, v0.w, a0.w);
        a1.x = fmaf(p, v1.x, a1.x); a1.y = fmaf(p, v1.y, a1.y);
        a1.z = fmaf(p, v1.z, a1.z); a1.w = fmaf(p, v1.w, a1.w);
        a2.x = fmaf(p, v2.x, a2.x); a2.y = fmaf(p, v2.y, a2.y);
        a2.z = fmaf(p, v2.z, a2.z); a2.w = fmaf(p, v2.w, a2.w);
        a3.x = fmaf(p, v3.x, a3.x); a3.y = fmaf(p, v3.y, a3.y);
        a3.z = fmaf(p, v3.z, a3.z); a3.w = fmaf(p, v3.w, a3.w);
    }
    float* ob = out + ((size_t)b * CC + h * HD + dbase) * HWN + n0 + lane;
    ob[0 * HWN]  = a0.x; ob[1 * HWN]  = a0.y; ob[2 * HWN]  = a0.z; ob[3 * HWN]  = a0.w;
    ob[4 * HWN]  = a1.x; ob[5 * HWN]  = a1.y; ob[6 * HWN]  = a1.z; ob[7 * HWN]  = a1.w;
    ob[8 * HWN]  = a2.x; ob[9 * HWN]  = a2.y; ob[10 * HWN] = a2.z; ob[11 * HWN] = a2.w;
    ob[12 * HWN] = a3.x; ob[13 * HWN] = a3.y; ob[14 * HWN] = a3.z; ob[15 * HWN] = a3.w;
}

extern "C" void kernel_launch(void* const* d_in, const int* in_sizes, int n_in,
                              void* d_out, int out_size, void* d_ws, size_t ws_size,
                              hipStream_t stream)
{
    const float* x     = (const float*)d_in[0];
    const float* te    = (const float*)d_in[1];
    const int*   amask = (const int*)d_in[2];
    const float* Wq    = (const float*)d_in[3];
    const float* bq    = (const float*)d_in[4];
    const float* Wk    = (const float*)d_in[5];
    const float* bk    = (const float*)d_in[6];
    const float* Wv    = (const float*)d_in[7];
    const float* bv    = (const float*)d_in[8];
    float* out = (float*)d_out;

    // Workspace: Q [B*N*C] + K [B*M*C] + V [B*M*C]  (~77 MB total)
    float* Qw = (float*)d_ws;
    float* Kw = Qw + (size_t)BB * HWN * CC;
    float* Vw = Kw + (size_t)BB * MM * CC;

    qgemm_kernel<<<dim3(16, 8, BB), 256, 0, stream>>>(x, Wq, bq, Qw);
    kvgemm_kernel<<<dim3(8, BB), 256, 0, stream>>>(te, Wk, bk, Wv, bv, Kw, Vw);
    attn_kernel<<<dim3(16, NH, BB), 256, 0, stream>>>(Qw, Kw, Vw, amask, out);
}

// Round 2
// 439.625 us; speedup vs baseline: 1.4639x; 1.4639x over previous
//
#include <hip/hip_runtime.h>
#include <math.h>

// Problem constants
#define BB   32
#define CC   512
#define HWN  1024   // H*W
#define MM   77
#define TXT  768
#define NH   8
#define HD   64
#define SCALEF 0.125f   // 1/sqrt(64)
#define KVROWS (BB*MM)  // 2464
#define AP   40         // padded LDS pitch (shorts) for MFMA operand tiles

typedef __attribute__((ext_vector_type(8))) short          bf16x8; // MFMA A/B frag (8 bf16)
typedef __attribute__((ext_vector_type(8))) unsigned short us8;
typedef __attribute__((ext_vector_type(4))) float          f32x4;  // MFMA C/D frag

__device__ inline unsigned short f2bf(float f) {
    union { float f; unsigned u; } v; v.f = f;
    unsigned r = v.u + 0x7fff + ((v.u >> 16) & 1);   // round-to-nearest-even
    return (unsigned short)(r >> 16);
}
__device__ inline float bf2f(unsigned short s) {
    union { unsigned u; float f; } v; v.u = ((unsigned)s) << 16; return v.f;
}

// ---------------------------------------------------------------------------
// xT[b][n][c] = x[b][c][n], fp32 -> bf16.  64x64 tiles via LDS.
// ---------------------------------------------------------------------------
__global__ __launch_bounds__(256) void tcvt_kernel(
    const float* __restrict__ x, unsigned short* __restrict__ xT)
{
    const int nt = blockIdx.x, ct = blockIdx.y, b = blockIdx.z;
    const int n0 = nt * 64, c0 = ct * 64;
    __shared__ float tile[64][65];
    const int t = threadIdx.x, tx = t & 15, ty = t >> 4;
    const float* xb = x + (size_t)b * CC * HWN;
    #pragma unroll
    for (int j = 0; j < 4; ++j) {
        const int c = ty + 16 * j;
        const float4 v = *(const float4*)&xb[(size_t)(c0 + c) * HWN + n0 + tx * 4];
        tile[c][tx * 4 + 0] = v.x; tile[c][tx * 4 + 1] = v.y;
        tile[c][tx * 4 + 2] = v.z; tile[c][tx * 4 + 3] = v.w;
    }
    __syncthreads();
    unsigned short* xTb = xT + (size_t)b * HWN * CC;
    #pragma unroll
    for (int j = 0; j < 4; ++j) {
        const int n = ty + 16 * j;
        ushort4 o;
        o.x = f2bf(tile[tx * 4 + 0][n]); o.y = f2bf(tile[tx * 4 + 1][n]);
        o.z = f2bf(tile[tx * 4 + 2][n]); o.w = f2bf(tile[tx * 4 + 3][n]);
        *(ushort4*)&xTb[(size_t)(n0 + n) * CC + c0 + tx * 4] = o;
    }
}

// ---------------------------------------------------------------------------
// Q(bf16)[row][co] = xT(bf16)[row][c] . Wq[co][c] + bq[co]
// 128x128 tile, BK=32, 4 waves (2x2), each wave 4x4 MFMA 16x16x32 tiles.
// A-frag: A[m=lane&15][k=quad*8+j]; B-frag: B[n=lane&15][k=quad*8+j];
// D: col=lane&15 (n), row=quad*4+reg (m).   [per m89/m91/m118 verified maps]
// ---------------------------------------------------------------------------
__global__ __launch_bounds__(256) void qgemm_mfma(
    const unsigned short* __restrict__ xT, const float* __restrict__ Wq,
    const float* __restrict__ bq, unsigned short* __restrict__ Qb)
{
    const int rt = blockIdx.x, ct = blockIdx.y;
    const int row0 = rt * 128, co0 = ct * 128;
    __shared__ unsigned short As[128 * AP];
    __shared__ unsigned short Bs[128 * AP];
    const int t = threadIdx.x;
    const int lane = t & 63, wv = t >> 6;
    const int wr = wv >> 1, wc = wv & 1;
    const int lm = lane & 15, quad = lane >> 4;
    const int chunk = t & 3, srow = t >> 2;   // staging: 4 lanes per row

    f32x4 acc[4][4] = {};

    for (int k0 = 0; k0 < CC; k0 += 32) {
        // stage A (bf16 copy, rows contiguous in k)
        #pragma unroll
        for (int p = 0; p < 2; ++p) {
            const int r = srow + p * 64;
            const us8 v = *(const us8*)&xT[(size_t)(row0 + r) * CC + k0 + chunk * 8];
            *(us8*)&As[r * AP + chunk * 8] = v;
        }
        // stage B (fp32 -> bf16 convert, Wq rows contiguous in k)
        #pragma unroll
        for (int p = 0; p < 2; ++p) {
            const int r = srow + p * 64;
            const float4 f0 = *(const float4*)&Wq[(size_t)(co0 + r) * CC + k0 + chunk * 8];
            const float4 f1 = *(const float4*)&Wq[(size_t)(co0 + r) * CC + k0 + chunk * 8 + 4];
            us8 o;
            o[0] = f2bf(f0.x); o[1] = f2bf(f0.y); o[2] = f2bf(f0.z); o[3] = f2bf(f0.w);
            o[4] = f2bf(f1.x); o[5] = f2bf(f1.y); o[6] = f2bf(f1.z); o[7] = f2bf(f1.w);
            *(us8*)&Bs[r * AP + chunk * 8] = o;
        }
        __syncthreads();
        bf16x8 a[4], bfr[4];
        #pragma unroll
        for (int i = 0; i < 4; ++i)
            a[i] = *(const bf16x8*)&As[(wr * 64 + i * 16 + lm) * AP + quad * 8];
        #pragma unroll
        for (int i = 0; i < 4; ++i)
            bfr[i] = *(const bf16x8*)&Bs[(wc * 64 + i * 16 + lm) * AP + quad * 8];
        #pragma unroll
        for (int mi = 0; mi < 4; ++mi)
            #pragma unroll
            for (int ni = 0; ni < 4; ++ni)
                acc[mi][ni] = __builtin_amdgcn_mfma_f32_16x16x32_bf16(
                    a[mi], bfr[ni], acc[mi][ni], 0, 0, 0);
        __syncthreads();
    }

    #pragma unroll
    for (int ni = 0; ni < 4; ++ni) {
        const int col = co0 + wc * 64 + ni * 16 + lm;
        const float bias = bq[col];
        #pragma unroll
        for (int mi = 0; mi < 4; ++mi) {
            #pragma unroll
            for (int j = 0; j < 4; ++j) {
                const int row = row0 + wr * 64 + mi * 16 + quad * 4 + j;
                Qb[(size_t)row * CC + col] = f2bf(acc[mi][ni][j] + bias);
            }
        }
    }
}

// ---------------------------------------------------------------------------
// K/V = te . {Wk,Wv}^T + {bk,bv}; te flat [2464][768], outputs fp32 [2464][512]
// Same structure as qgemm; ct<4 -> K cols, ct>=4 -> V cols. fp32 A staged+cvt.
// ---------------------------------------------------------------------------
__global__ __launch_bounds__(256) void kvgemm_mfma(
    const float* __restrict__ te,
    const float* __restrict__ Wk, const float* __restrict__ bk,
    const float* __restrict__ Wv, const float* __restrict__ bv,
    float* __restrict__ K, float* __restrict__ V)
{
    const int rt = blockIdx.x, ct = blockIdx.y;
    const int row0 = rt * 128;
    const int isV = (ct >= 4);
    const float* W = isV ? Wv : Wk;
    const float* bias_p = isV ? bv : bk;
    float* outp = isV ? V : K;
    const int co0 = (ct & 3) * 128;

    __shared__ unsigned short As[128 * AP];
    __shared__ unsigned short Bs[128 * AP];
    const int t = threadIdx.x;
    const int lane = t & 63, wv_ = t >> 6;
    const int wr = wv_ >> 1, wc = wv_ & 1;
    const int lm = lane & 15, quad = lane >> 4;
    const int chunk = t & 3, srow = t >> 2;

    f32x4 acc[4][4] = {};

    for (int k0 = 0; k0 < TXT; k0 += 32) {
        #pragma unroll
        for (int p = 0; p < 2; ++p) {
            const int r = srow + p * 64;
            const int rg = min(row0 + r, KVROWS - 1);
            const float4 f0 = *(const float4*)&te[(size_t)rg * TXT + k0 + chunk * 8];
            const float4 f1 = *(const float4*)&te[(size_t)rg * TXT + k0 + chunk * 8 + 4];
            us8 o;
            o[0] = f2bf(f0.x); o[1] = f2bf(f0.y); o[2] = f2bf(f0.z); o[3] = f2bf(f0.w);
            o[4] = f2bf(f1.x); o[5] = f2bf(f1.y); o[6] = f2bf(f1.z); o[7] = f2bf(f1.w);
            *(us8*)&As[r * AP + chunk * 8] = o;
        }
        #pragma unroll
        for (int p = 0; p < 2; ++p) {
            const int r = srow + p * 64;
            const float4 f0 = *(const float4*)&W[(size_t)(co0 + r) * TXT + k0 + chunk * 8];
            const float4 f1 = *(const float4*)&W[(size_t)(co0 + r) * TXT + k0 + chunk * 8 + 4];
            us8 o;
            o[0] = f2bf(f0.x); o[1] = f2bf(f0.y); o[2] = f2bf(f0.z); o[3] = f2bf(f0.w);
            o[4] = f2bf(f1.x); o[5] = f2bf(f1.y); o[6] = f2bf(f1.z); o[7] = f2bf(f1.w);
            *(us8*)&Bs[r * AP + chunk * 8] = o;
        }
        __syncthreads();
        bf16x8 a[4], bfr[4];
        #pragma unroll
        for (int i = 0; i < 4; ++i)
            a[i] = *(const bf16x8*)&As[(wr * 64 + i * 16 + lm) * AP + quad * 8];
        #pragma unroll
        for (int i = 0; i < 4; ++i)
            bfr[i] = *(const bf16x8*)&Bs[(wc * 64 + i * 16 + lm) * AP + quad * 8];
        #pragma unroll
        for (int mi = 0; mi < 4; ++mi)
            #pragma unroll
            for (int ni = 0; ni < 4; ++ni)
                acc[mi][ni] = __builtin_amdgcn_mfma_f32_16x16x32_bf16(
                    a[mi], bfr[ni], acc[mi][ni], 0, 0, 0);
        __syncthreads();
    }

    #pragma unroll
    for (int ni = 0; ni < 4; ++ni) {
        const int col = co0 + wc * 64 + ni * 16 + lm;
        const float bias = bias_p[col];
        #pragma unroll
        for (int mi = 0; mi < 4; ++mi) {
            #pragma unroll
            for (int j = 0; j < 4; ++j) {
                const int row = row0 + wr * 64 + mi * 16 + quad * 4 + j;
                if (row < KVROWS)
                    outp[(size_t)row * CC + col] = acc[mi][ni][j] + bias;
            }
        }
    }
}

// ---------------------------------------------------------------------------
// Attention (fp32 math, Q read as bf16): per (b, h, 64-row n tile).
// ---------------------------------------------------------------------------
__global__ __launch_bounds__(256) void attn_kernel(
    const unsigned short* __restrict__ Qb, const float* __restrict__ K,
    const float* __restrict__ V, const int* __restrict__ amask,
    float* __restrict__ out)
{
    const int nt = blockIdx.x;      // 0..15
    const int h  = blockIdx.y;      // 0..7
    const int b  = blockIdx.z;      // 0..31
    const int n0 = nt * 64;

    __shared__ float Ks[MM][68];
    __shared__ float Vs[MM][68];
    __shared__ float Ps[64][MM];
    __shared__ int   msk[MM];

    const int t = threadIdx.x;

    for (int idx = t; idx < MM * 16; idx += 256) {
        const int m = idx >> 4, k4 = (idx & 15) * 4;
        const float4 kv = *(const float4*)&K[((size_t)b * MM + m) * CC + h * HD + k4];
        *(float4*)&Ks[m][k4] = kv;
        const float4 vv = *(const float4*)&V[((size_t)b * MM + m) * CC + h * HD + k4];
        *(float4*)&Vs[m][k4] = vv;
    }
    if (t < MM) msk[t] = amask[b * MM + t];

    const int r = t >> 2;           // 0..63
    const int q = t & 3;            // k-chunk
    const unsigned short* qrow = Qb + ((size_t)(b * HWN + n0 + r)) * CC + h * HD + q * 16;
    float qv[16];
    {
        const us8 qa = *(const us8*)&qrow[0];
        const us8 qb2 = *(const us8*)&qrow[8];
        #pragma unroll
        for (int i = 0; i < 8; ++i) {
            qv[i]     = bf2f((unsigned short)qa[i]);
            qv[8 + i] = bf2f((unsigned short)qb2[i]);
        }
    }

    __syncthreads();

    float s[20];
    const int cnt = (80 - q) >> 2;  // 20,19,19,19
    for (int m = 0; m < MM; ++m) {
        const float* kr = &Ks[m][q * 16];
        float p = 0.f;
        #pragma unroll
        for (int i = 0; i < 16; ++i) p = fmaf(qv[i], kr[i], p);
        p += __shfl_xor(p, 1, 64);
        p += __shfl_xor(p, 2, 64);
        if ((m & 3) == q) s[m >> 2] = p * SCALEF;
    }

    float mx = -INFINITY;
    #pragma unroll
    for (int i = 0; i < 20; ++i) {
        if (i < cnt) {
            const int m = 4 * i + q;
            if (msk[m] == 0) s[i] = -INFINITY;
            mx = fmaxf(mx, s[i]);
        }
    }
    mx = fmaxf(mx, __shfl_xor(mx, 1, 64));
    mx = fmaxf(mx, __shfl_xor(mx, 2, 64));
    float sum = 0.f;
    #pragma unroll
    for (int i = 0; i < 20; ++i) {
        if (i < cnt) {
            const float e = __expf(s[i] - mx);
            s[i] = e;
            sum += e;
        }
    }
    sum += __shfl_xor(sum, 1, 64);
    sum += __shfl_xor(sum, 2, 64);
    const float inv = 1.0f / sum;
    #pragma unroll
    for (int i = 0; i < 20; ++i)
        if (i < cnt) Ps[r][4 * i + q] = s[i] * inv;

    __syncthreads();

    const int w     = t >> 6;
    const int lane  = t & 63;
    const int dbase = w * 16;
    float4 a0 = make_float4(0, 0, 0, 0), a1 = a0, a2 = a0, a3 = a0;
    for (int m = 0; m < MM; ++m) {
        const float p = Ps[lane][m];
        const float4 v0 = *(const float4*)&Vs[m][dbase + 0];
        const float4 v1 = *(const float4*)&Vs[m][dbase + 4];
        const float4 v2 = *(const float4*)&Vs[m][dbase + 8];
        const float4 v3 = *(const float4*)&Vs[m][dbase + 12];
        a0.x = fmaf(p, v0.x, a0.x); a0.y = fmaf(p, v0.y, a0.y);
        a0.z = fmaf(p, v0.z, a0.z); a0.w = fmaf(p, v0.w, a0.w);
        a1.x = fmaf(p, v1.x, a1.x); a1.y = fmaf(p, v1.y, a1.y);
        a1.z = fmaf(p, v1.z, a1.z); a1.w = fmaf(p, v1.w, a1.w);
        a2.x = fmaf(p, v2.x, a2.x); a2.y = fmaf(p, v2.y, a2.y);
        a2.z = fmaf(p, v2.z, a2.z); a2.w = fmaf(p, v2.w, a2.w);
        a3.x = fmaf(p, v3.x, a3.x); a3.y = fmaf(p, v3.y, a3.y);
        a3.z = fmaf(p, v3.z, a3.z); a3.w = fmaf(p, v3.w, a3.w);
    }
    float* ob = out + ((size_t)b * CC + h * HD + dbase) * HWN + n0 + lane;
    ob[0 * HWN]  = a0.x; ob[1 * HWN]  = a0.y; ob[2 * HWN]  = a0.z; ob[3 * HWN]  = a0.w;
    ob[4 * HWN]  = a1.x; ob[5 * HWN]  = a1.y; ob[6 * HWN]  = a1.z; ob[7 * HWN]  = a1.w;
    ob[8 * HWN]  = a2.x; ob[9 * HWN]  = a2.y; ob[10 * HWN] = a2.z; ob[11 * HWN] = a2.w;
    ob[12 * HWN] = a3.x; ob[13 * HWN] = a3.y; ob[14 * HWN] = a3.z; ob[15 * HWN] = a3.w;
}

extern "C" void kernel_launch(void* const* d_in, const int* in_sizes, int n_in,
                              void* d_out, int out_size, void* d_ws, size_t ws_size,
                              hipStream_t stream)
{
    const float* x     = (const float*)d_in[0];
    const float* te    = (const float*)d_in[1];
    const int*   amask = (const int*)d_in[2];
    const float* Wq    = (const float*)d_in[3];
    const float* bq    = (const float*)d_in[4];
    const float* Wk    = (const float*)d_in[5];
    const float* bk    = (const float*)d_in[6];
    const float* Wv    = (const float*)d_in[7];
    const float* bv    = (const float*)d_in[8];
    float* out = (float*)d_out;

    // Workspace (77.2 MB, same total as R1):
    //   xT bf16 [32768][512], Qb bf16 [32768][512], Kw/Vw fp32 [2464][512]
    unsigned short* xT = (unsigned short*)d_ws;
    unsigned short* Qb = xT + (size_t)BB * HWN * CC;
    float* Kw = (float*)(Qb + (size_t)BB * HWN * CC);
    float* Vw = Kw + (size_t)KVROWS * CC;

    tcvt_kernel<<<dim3(16, 8, BB), 256, 0, stream>>>(x, xT);
    qgemm_mfma<<<dim3(256, 4), 256, 0, stream>>>(xT, Wq, bq, Qb);
    kvgemm_mfma<<<dim3(20, 8), 256, 0, stream>>>(te, Wk, bk, Wv, bv, Kw, Vw);
    attn_kernel<<<dim3(16, NH, BB), 256, 0, stream>>>(Qb, Kw, Vw, amask, out);
}

// Round 3
// 243.400 us; speedup vs baseline: 2.6440x; 1.8062x over previous
//
#include <hip/hip_runtime.h>
#include <math.h>

// Problem constants
#define BB   32
#define CC   512
#define HWN  1024   // H*W
#define MM   77
#define TXT  768
#define NH   8
#define HD   64
#define SCALEF 0.125f   // 1/sqrt(64)
#define MPAD 96         // padded M for PV K-dim (3 x 32)
#define KVROWS (BB*MPAD) // 3072 padded row space for kvgemm
#define AP   40         // padded LDS pitch (shorts) for GEMM operand tiles
#define PP   104        // Ps pitch in shorts (104*2=208=13*16B, aligned)

typedef __attribute__((ext_vector_type(8))) short          bf16x8; // MFMA A/B frag
typedef __attribute__((ext_vector_type(8))) unsigned short us8;
typedef __attribute__((ext_vector_type(4))) float          f32x4;  // MFMA C/D frag

__device__ inline unsigned short f2bf(float f) {
    union { float f; unsigned u; } v; v.f = f;
    unsigned r = v.u + 0x7fff + ((v.u >> 16) & 1);   // RNE
    return (unsigned short)(r >> 16);
}

// ---------------------------------------------------------------------------
// Wq fp32 -> bf16 (one-shot; 512*512 elems = 65536 float4)
// ---------------------------------------------------------------------------
__global__ __launch_bounds__(256) void wcvt_kernel(
    const float* __restrict__ src, unsigned short* __restrict__ dst)
{
    const int i = blockIdx.x * 256 + threadIdx.x;   // grid sized exactly
    const float4 v = ((const float4*)src)[i];
    ushort4 o;
    o.x = f2bf(v.x); o.y = f2bf(v.y); o.z = f2bf(v.z); o.w = f2bf(v.w);
    ((ushort4*)dst)[i] = o;
}

// ---------------------------------------------------------------------------
// xT[b][n][c] = x[b][c][n], fp32 -> bf16.  64x64 tiles via LDS.
// ---------------------------------------------------------------------------
__global__ __launch_bounds__(256) void tcvt_kernel(
    const float* __restrict__ x, unsigned short* __restrict__ xT)
{
    const int nt = blockIdx.x, ct = blockIdx.y, b = blockIdx.z;
    const int n0 = nt * 64, c0 = ct * 64;
    __shared__ float tile[64][65];
    const int t = threadIdx.x, tx = t & 15, ty = t >> 4;
    const float* xb = x + (size_t)b * CC * HWN;
    #pragma unroll
    for (int j = 0; j < 4; ++j) {
        const int c = ty + 16 * j;
        const float4 v = *(const float4*)&xb[(size_t)(c0 + c) * HWN + n0 + tx * 4];
        tile[c][tx * 4 + 0] = v.x; tile[c][tx * 4 + 1] = v.y;
        tile[c][tx * 4 + 2] = v.z; tile[c][tx * 4 + 3] = v.w;
    }
    __syncthreads();
    unsigned short* xTb = xT + (size_t)b * HWN * CC;
    #pragma unroll
    for (int j = 0; j < 4; ++j) {
        const int n = ty + 16 * j;
        ushort4 o;
        o.x = f2bf(tile[tx * 4 + 0][n]); o.y = f2bf(tile[tx * 4 + 1][n]);
        o.z = f2bf(tile[tx * 4 + 2][n]); o.w = f2bf(tile[tx * 4 + 3][n]);
        *(ushort4*)&xTb[(size_t)(n0 + n) * CC + c0 + tx * 4] = o;
    }
}

// ---------------------------------------------------------------------------
// Q(bf16)[row][co] = xT(bf16)[row][c] . Wqb(bf16)[co][c] + bq[co]
// 128x128 tile, BK=32, 4 waves (2x2), each wave 4x4 MFMA 16x16x32 tiles.
// ---------------------------------------------------------------------------
__global__ __launch_bounds__(256) void qgemm_mfma(
    const unsigned short* __restrict__ xT, const unsigned short* __restrict__ Wqb,
    const float* __restrict__ bq, unsigned short* __restrict__ Qb)
{
    const int rt = blockIdx.x, ct = blockIdx.y;
    const int row0 = rt * 128, co0 = ct * 128;
    __shared__ unsigned short As[128 * AP];
    __shared__ unsigned short Bs[128 * AP];
    const int t = threadIdx.x;
    const int lane = t & 63, wv = t >> 6;
    const int wr = wv >> 1, wc = wv & 1;
    const int lm = lane & 15, quad = lane >> 4;
    const int chunk = t & 3, srow = t >> 2;

    f32x4 acc[4][4] = {};

    for (int k0 = 0; k0 < CC; k0 += 32) {
        #pragma unroll
        for (int p = 0; p < 2; ++p) {
            const int r = srow + p * 64;
            *(us8*)&As[r * AP + chunk * 8] =
                *(const us8*)&xT[(size_t)(row0 + r) * CC + k0 + chunk * 8];
            *(us8*)&Bs[r * AP + chunk * 8] =
                *(const us8*)&Wqb[(size_t)(co0 + r) * CC + k0 + chunk * 8];
        }
        __syncthreads();
        bf16x8 a[4], bfr[4];
        #pragma unroll
        for (int i = 0; i < 4; ++i)
            a[i] = *(const bf16x8*)&As[(wr * 64 + i * 16 + lm) * AP + quad * 8];
        #pragma unroll
        for (int i = 0; i < 4; ++i)
            bfr[i] = *(const bf16x8*)&Bs[(wc * 64 + i * 16 + lm) * AP + quad * 8];
        #pragma unroll
        for (int mi = 0; mi < 4; ++mi)
            #pragma unroll
            for (int ni = 0; ni < 4; ++ni)
                acc[mi][ni] = __builtin_amdgcn_mfma_f32_16x16x32_bf16(
                    a[mi], bfr[ni], acc[mi][ni], 0, 0, 0);
        __syncthreads();
    }

    #pragma unroll
    for (int ni = 0; ni < 4; ++ni) {
        const int col = co0 + wc * 64 + ni * 16 + lm;
        const float bias = bq[col];
        #pragma unroll
        for (int mi = 0; mi < 4; ++mi) {
            #pragma unroll
            for (int j = 0; j < 4; ++j) {
                const int row = row0 + wr * 64 + mi * 16 + quad * 4 + j;
                Qb[(size_t)row * CC + col] = f2bf(acc[mi][ni][j] + bias);
            }
        }
    }
}

// ---------------------------------------------------------------------------
// K/V GEMM over padded row space (b*96+m, 3072 rows).
// ct<4: Kb bf16 [B*77][512] (skip pad rows).  ct>=4: Vt bf16 [B][512][96]
// (pad rows written with garbage-but-finite values; attention P is zero there).
// ---------------------------------------------------------------------------
__global__ __launch_bounds__(256) void kvgemm_mfma(
    const float* __restrict__ te,
    const float* __restrict__ Wk, const float* __restrict__ bk,
    const float* __restrict__ Wv, const float* __restrict__ bv,
    unsigned short* __restrict__ Kb, unsigned short* __restrict__ Vt)
{
    const int rt = blockIdx.x, ct = blockIdx.y;
    const int row0 = rt * 128;
    const int isV = (ct >= 4);
    const float* W = isV ? Wv : Wk;
    const float* bias_p = isV ? bv : bk;
    const int co0 = (ct & 3) * 128;

    __shared__ unsigned short As[128 * AP];
    __shared__ unsigned short Bs[128 * AP];
    const int t = threadIdx.x;
    const int lane = t & 63, wv_ = t >> 6;
    const int wr = wv_ >> 1, wc = wv_ & 1;
    const int lm = lane & 15, quad = lane >> 4;
    const int chunk = t & 3, srow = t >> 2;

    f32x4 acc[4][4] = {};

    for (int k0 = 0; k0 < TXT; k0 += 32) {
        #pragma unroll
        for (int p = 0; p < 2; ++p) {
            const int r = srow + p * 64;
            const int rflat = row0 + r;
            const int b_i = rflat / MPAD, m_i = rflat % MPAD;
            const float* terow = te + ((size_t)b_i * MM + min(m_i, MM - 1)) * TXT;
            const float4 f0 = *(const float4*)&terow[k0 + chunk * 8];
            const float4 f1 = *(const float4*)&terow[k0 + chunk * 8 + 4];
            us8 o;
            o[0] = f2bf(f0.x); o[1] = f2bf(f0.y); o[2] = f2bf(f0.z); o[3] = f2bf(f0.w);
            o[4] = f2bf(f1.x); o[5] = f2bf(f1.y); o[6] = f2bf(f1.z); o[7] = f2bf(f1.w);
            *(us8*)&As[r * AP + chunk * 8] = o;

            const float4 g0 = *(const float4*)&W[(size_t)(co0 + r) * TXT + k0 + chunk * 8];
            const float4 g1 = *(const float4*)&W[(size_t)(co0 + r) * TXT + k0 + chunk * 8 + 4];
            us8 ob;
            ob[0] = f2bf(g0.x); ob[1] = f2bf(g0.y); ob[2] = f2bf(g0.z); ob[3] = f2bf(g0.w);
            ob[4] = f2bf(g1.x); ob[5] = f2bf(g1.y); ob[6] = f2bf(g1.z); ob[7] = f2bf(g1.w);
            *(us8*)&Bs[r * AP + chunk * 8] = ob;
        }
        __syncthreads();
        bf16x8 a[4], bfr[4];
        #pragma unroll
        for (int i = 0; i < 4; ++i)
            a[i] = *(const bf16x8*)&As[(wr * 64 + i * 16 + lm) * AP + quad * 8];
        #pragma unroll
        for (int i = 0; i < 4; ++i)
            bfr[i] = *(const bf16x8*)&Bs[(wc * 64 + i * 16 + lm) * AP + quad * 8];
        #pragma unroll
        for (int mi = 0; mi < 4; ++mi)
            #pragma unroll
            for (int ni = 0; ni < 4; ++ni)
                acc[mi][ni] = __builtin_amdgcn_mfma_f32_16x16x32_bf16(
                    a[mi], bfr[ni], acc[mi][ni], 0, 0, 0);
        __syncthreads();
    }

    #pragma unroll
    for (int ni = 0; ni < 4; ++ni) {
        const int col = co0 + wc * 64 + ni * 16 + lm;
        const float bias = bias_p[col];
        #pragma unroll
        for (int mi = 0; mi < 4; ++mi) {
            #pragma unroll
            for (int j = 0; j < 4; ++j) {
                const int row = row0 + wr * 64 + mi * 16 + quad * 4 + j;
                const int b_i = row / MPAD, m_i = row % MPAD;
                const unsigned short hv = f2bf(acc[mi][ni][j] + bias);
                if (isV) {
                    Vt[((size_t)b_i * CC + col) * MPAD + m_i] = hv;
                } else if (m_i < MM) {
                    Kb[((size_t)b_i * MM + m_i) * CC + col] = hv;
                }
            }
        }
    }
}

// ---------------------------------------------------------------------------
// MFMA attention: block = (128 Q rows, head h, batch b). 4 waves, each wave
// owns 32 rows (2 m-tiles). QK^T via mfma (K=64), softmax in C-layout regs,
// exp(P) -> LDS A-layout bf16, PV via mfma (K=96 padded), epilogue scales by
// 1/sum from regs. Output written [B,C,N].
// ---------------------------------------------------------------------------
__global__ __launch_bounds__(256) void attn_mfma(
    const unsigned short* __restrict__ Qb, const unsigned short* __restrict__ Kb,
    const unsigned short* __restrict__ Vt, const int* __restrict__ amask,
    float* __restrict__ out)
{
    const int ntile = blockIdx.x;   // 0..7
    const int h     = blockIdx.y;   // 0..7
    const int b     = blockIdx.z;   // 0..31
    const int row0  = ntile * 128;

    __shared__ unsigned short Ps[128 * PP];
    __shared__ float msk[80];

    const int t = threadIdx.x;
    const int w = t >> 6, lane = t & 63;
    const int lm = lane & 15, quad = lane >> 4;

    // zero-fill Ps[:, 80..96) so PV's pad-K reads are clean
    {
        const int r = t >> 1, off = 80 + (t & 1) * 8;
        us8 z = {0, 0, 0, 0, 0, 0, 0, 0};
        *(us8*)&Ps[r * PP + off] = z;
    }
    if (t < 80) msk[t] = (t < MM && amask[b * MM + t] != 0) ? 0.f : -INFINITY;
    __syncthreads();

    // ---- Phase 1: scores = Q K^T ----
    f32x4 s[2][5] = {};
    const unsigned short* qbase = Qb + ((size_t)b * HWN + row0) * CC + h * HD;
    const unsigned short* kbase = Kb + (size_t)b * MM * CC + h * HD;
    #pragma unroll
    for (int ks = 0; ks < 2; ++ks) {
        bf16x8 a[2], kf[5];
        #pragma unroll
        for (int mt = 0; mt < 2; ++mt)
            a[mt] = *(const bf16x8*)&qbase[(size_t)((w * 2 + mt) * 16 + lm) * CC + ks * 32 + quad * 8];
        #pragma unroll
        for (int n = 0; n < 5; ++n) {
            const int kr = min(n * 16 + lm, MM - 1);
            kf[n] = *(const bf16x8*)&kbase[(size_t)kr * CC + ks * 32 + quad * 8];
        }
        #pragma unroll
        for (int mt = 0; mt < 2; ++mt)
            #pragma unroll
            for (int n = 0; n < 5; ++n)
                s[mt][n] = __builtin_amdgcn_mfma_f32_16x16x32_bf16(a[mt], kf[n], s[mt][n], 0, 0, 0);
    }

    // ---- Phase 2: masked softmax per row (row = (w*2+mt)*16 + quad*4 + j) ----
    float inv[2][4];
    #pragma unroll
    for (int mt = 0; mt < 2; ++mt) {
        #pragma unroll
        for (int j = 0; j < 4; ++j) {
            float v[5];
            #pragma unroll
            for (int n = 0; n < 5; ++n)
                v[n] = s[mt][n][j] * SCALEF + msk[n * 16 + lm];
            float mx = fmaxf(fmaxf(fmaxf(v[0], v[1]), fmaxf(v[2], v[3])), v[4]);
            mx = fmaxf(mx, __shfl_xor(mx, 1, 64));
            mx = fmaxf(mx, __shfl_xor(mx, 2, 64));
            mx = fmaxf(mx, __shfl_xor(mx, 4, 64));
            mx = fmaxf(mx, __shfl_xor(mx, 8, 64));
            float sum = 0.f;
            #pragma unroll
            for (int n = 0; n < 5; ++n) { v[n] = __expf(v[n] - mx); sum += v[n]; }
            sum += __shfl_xor(sum, 1, 64);
            sum += __shfl_xor(sum, 2, 64);
            sum += __shfl_xor(sum, 4, 64);
            sum += __shfl_xor(sum, 8, 64);
            inv[mt][j] = 1.0f / sum;
            const int mrow = (w * 2 + mt) * 16 + quad * 4 + j;
            #pragma unroll
            for (int n = 0; n < 5; ++n)
                Ps[mrow * PP + n * 16 + lm] = f2bf(v[n]);
        }
    }
    __syncthreads();

    // ---- Phase 3: O = P V ----
    f32x4 o[2][4] = {};
    const unsigned short* vbase = Vt + ((size_t)b * CC + h * HD) * MPAD;
    #pragma unroll
    for (int ks = 0; ks < 3; ++ks) {
        bf16x8 a[2], vf[4];
        #pragma unroll
        for (int mt = 0; mt < 2; ++mt)
            a[mt] = *(const bf16x8*)&Ps[((w * 2 + mt) * 16 + lm) * PP + ks * 32 + quad * 8];
        #pragma unroll
        for (int n = 0; n < 4; ++n)
            vf[n] = *(const bf16x8*)&vbase[(size_t)(n * 16 + lm) * MPAD + ks * 32 + quad * 8];
        #pragma unroll
        for (int mt = 0; mt < 2; ++mt)
            #pragma unroll
            for (int n = 0; n < 4; ++n)
                o[mt][n] = __builtin_amdgcn_mfma_f32_16x16x32_bf16(a[mt], vf[n], o[mt][n], 0, 0, 0);
    }

    // ---- Epilogue: out[b][h*64+col][row0 + r] = o * inv ----
    float* obase = out + ((size_t)b * CC + h * HD) * HWN + row0;
    #pragma unroll
    for (int mt = 0; mt < 2; ++mt) {
        #pragma unroll
        for (int n = 0; n < 4; ++n) {
            const int col = n * 16 + lm;
            #pragma unroll
            for (int j = 0; j < 4; ++j) {
                const int r = (w * 2 + mt) * 16 + quad * 4 + j;
                obase[(size_t)col * HWN + r] = o[mt][n][j] * inv[mt][j];
            }
        }
    }
}

extern "C" void kernel_launch(void* const* d_in, const int* in_sizes, int n_in,
                              void* d_out, int out_size, void* d_ws, size_t ws_size,
                              hipStream_t stream)
{
    const float* x     = (const float*)d_in[0];
    const float* te    = (const float*)d_in[1];
    const int*   amask = (const int*)d_in[2];
    const float* Wq    = (const float*)d_in[3];
    const float* bq    = (const float*)d_in[4];
    const float* Wk    = (const float*)d_in[5];
    const float* bk    = (const float*)d_in[6];
    const float* Wv    = (const float*)d_in[7];
    const float* bv    = (const float*)d_in[8];
    float* out = (float*)d_out;

    // Workspace (73.3 MB):
    //   xT  bf16 [32][1024][512]  33.55 MB
    //   Qb  bf16 [32][1024][512]  33.55 MB
    //   Kb  bf16 [32*77][512]      2.52 MB
    //   Vt  bf16 [32][512][96]     3.15 MB
    //   Wqb bf16 [512][512]        0.52 MB
    unsigned short* xT  = (unsigned short*)d_ws;
    unsigned short* Qb  = xT + (size_t)BB * HWN * CC;
    unsigned short* Kb  = Qb + (size_t)BB * HWN * CC;
    unsigned short* Vt  = Kb + (size_t)BB * MM * CC;
    unsigned short* Wqb = Vt + (size_t)BB * CC * MPAD;

    wcvt_kernel<<<dim3(CC * CC / 4 / 256), 256, 0, stream>>>(Wq, Wqb);
    tcvt_kernel<<<dim3(16, 8, BB), 256, 0, stream>>>(x, xT);
    qgemm_mfma<<<dim3(256, 4), 256, 0, stream>>>(xT, Wqb, bq, Qb);
    kvgemm_mfma<<<dim3(KVROWS / 128, 8), 256, 0, stream>>>(te, Wk, bk, Wv, bv, Kb, Vt);
    attn_mfma<<<dim3(8, NH, BB), 256, 0, stream>>>(Qb, Kb, Vt, amask, out);
}

// Round 4
// 233.239 us; speedup vs baseline: 2.7592x; 1.0436x over previous
//
#include <hip/hip_runtime.h>
#include <math.h>

// Problem constants
#define BB   32
#define CC   512
#define HWN  1024   // H*W
#define MM   77
#define TXT  768
#define NH   8
#define HD   64
#define SCALEF 0.125f   // 1/sqrt(64)
#define MPAD 96          // padded M for PV K-dim (3 x 32)
#define KVROWS (BB*MPAD) // 3072 padded row space for kvgemm
#define AP   40          // padded LDS pitch (shorts) for kvgemm operand tiles
#define PP   104         // Ps pitch in shorts (104*2=208=13*16B, aligned)
#define OSP  132         // Os pitch in floats (multiple of 4 for float4 align)

typedef __attribute__((ext_vector_type(8))) short          bf16x8; // MFMA A/B frag
typedef __attribute__((ext_vector_type(8))) unsigned short us8;
typedef __attribute__((ext_vector_type(4))) float          f32x4;  // MFMA C/D frag

__device__ inline unsigned short f2bf(float f) {
    union { float f; unsigned u; } v; v.f = f;
    unsigned r = v.u + 0x7fff + ((v.u >> 16) & 1);   // RNE
    return (unsigned short)(r >> 16);
}

__device__ inline void gload_lds16(const void* g, void* l) {
    __builtin_amdgcn_global_load_lds(
        (const __attribute__((address_space(1))) void*)g,
        (__attribute__((address_space(3))) void*)l, 16, 0, 0);
}

// ---------------------------------------------------------------------------
// Wq fp32 -> bf16 (one-shot; 512*512 elems = 65536 float4)
// ---------------------------------------------------------------------------
__global__ __launch_bounds__(256) void wcvt_kernel(
    const float* __restrict__ src, unsigned short* __restrict__ dst)
{
    const int i = blockIdx.x * 256 + threadIdx.x;
    const float4 v = ((const float4*)src)[i];
    ushort4 o;
    o.x = f2bf(v.x); o.y = f2bf(v.y); o.z = f2bf(v.z); o.w = f2bf(v.w);
    ((ushort4*)dst)[i] = o;
}

// ---------------------------------------------------------------------------
// xT[b][n][c] = x[b][c][n], fp32 -> bf16.  64x64 tiles via LDS, us8 stores.
// ---------------------------------------------------------------------------
__global__ __launch_bounds__(256) void tcvt_kernel(
    const float* __restrict__ x, unsigned short* __restrict__ xT)
{
    const int nt = blockIdx.x, ct = blockIdx.y, b = blockIdx.z;
    const int n0 = nt * 64, c0 = ct * 64;
    __shared__ float tile[64][65];
    const int t = threadIdx.x;
    const float* xb = x + (size_t)b * CC * HWN;
    {
        const int c = t >> 2;
        #pragma unroll
        for (int j = 0; j < 4; ++j) {
            const int f4 = (t & 3) + j * 4;
            const float4 v = *(const float4*)&xb[(size_t)(c0 + c) * HWN + n0 + f4 * 4];
            tile[c][f4 * 4 + 0] = v.x; tile[c][f4 * 4 + 1] = v.y;
            tile[c][f4 * 4 + 2] = v.z; tile[c][f4 * 4 + 3] = v.w;
        }
    }
    __syncthreads();
    unsigned short* xTb = xT + (size_t)b * HWN * CC;
    #pragma unroll
    for (int j = 0; j < 2; ++j) {
        const int n = (t >> 3) + j * 32;
        const int c8 = (t & 7) * 8;
        us8 o;
        #pragma unroll
        for (int i = 0; i < 8; ++i) o[i] = f2bf(tile[c8 + i][n]);
        *(us8*)&xTb[(size_t)(n0 + n) * CC + c0 + c8] = o;
    }
}

// ---------------------------------------------------------------------------
// Q(bf16)[row][co] = xT . Wqb^T + bq.  m97 pattern: 128x128 tile, BK=32,
// unpadded pitch-32 LDS, 16B global_load_lds staging, 4 waves 2x2, 4x4 tiles.
// ---------------------------------------------------------------------------
__global__ __launch_bounds__(256) void qgemm_mfma(
    const unsigned short* __restrict__ xT, const unsigned short* __restrict__ Wqb,
    const float* __restrict__ bq, unsigned short* __restrict__ Qb)
{
    const int rt = blockIdx.x, ct = blockIdx.y;
    const int row0 = rt * 128, co0 = ct * 128;
    __shared__ unsigned short As[128 * 32];
    __shared__ unsigned short Bs[128 * 32];
    const int t = threadIdx.x;
    const int lane = t & 63, w = t >> 6;
    const int wr = w >> 1, wc = w & 1;
    const int lm = lane & 15, quad = lane >> 4;
    const int lrow = lane >> 2, lk = (lane & 3) * 8;   // staging lane mapping

    f32x4 acc[4][4] = {};

    for (int k0 = 0; k0 < CC; k0 += 32) {
        #pragma unroll
        for (int p = 0; p < 2; ++p) {
            const int chunk = w * 2 + p;               // 0..7, 16 rows each
            gload_lds16(&xT[(size_t)(row0 + chunk * 16 + lrow) * CC + k0 + lk],
                        &As[chunk * 512]);
            gload_lds16(&Wqb[(size_t)(co0 + chunk * 16 + lrow) * CC + k0 + lk],
                        &Bs[chunk * 512]);
        }
        __syncthreads();
        bf16x8 a[4], bfr[4];
        #pragma unroll
        for (int i = 0; i < 4; ++i)
            a[i] = *(const bf16x8*)&As[(wr * 64 + i * 16 + lm) * 32 + quad * 8];
        #pragma unroll
        for (int i = 0; i < 4; ++i)
            bfr[i] = *(const bf16x8*)&Bs[(wc * 64 + i * 16 + lm) * 32 + quad * 8];
        #pragma unroll
        for (int mi = 0; mi < 4; ++mi)
            #pragma unroll
            for (int ni = 0; ni < 4; ++ni)
                acc[mi][ni] = __builtin_amdgcn_mfma_f32_16x16x32_bf16(
                    a[mi], bfr[ni], acc[mi][ni], 0, 0, 0);
        __syncthreads();
    }

    #pragma unroll
    for (int ni = 0; ni < 4; ++ni) {
        const int col = co0 + wc * 64 + ni * 16 + lm;
        const float bias = bq[col];
        #pragma unroll
        for (int mi = 0; mi < 4; ++mi) {
            #pragma unroll
            for (int j = 0; j < 4; ++j) {
                const int row = row0 + wr * 64 + mi * 16 + quad * 4 + j;
                Qb[(size_t)row * CC + col] = f2bf(acc[mi][ni][j] + bias);
            }
        }
    }
}

// ---------------------------------------------------------------------------
// K/V GEMM, 64x64 tiles over (3072 padded rows x 1024 cols [K|V]).
// grid (48, 16): ctc<8 -> K cols, ctc>=8 -> V cols. 768 blocks for occupancy.
// On-the-fly fp32->bf16 convert staging (VALU was idle; latency was the issue).
// ---------------------------------------------------------------------------
__global__ __launch_bounds__(256) void kvgemm_mfma(
    const float* __restrict__ te,
    const float* __restrict__ Wk, const float* __restrict__ bk,
    const float* __restrict__ Wv, const float* __restrict__ bv,
    unsigned short* __restrict__ Kb, unsigned short* __restrict__ Vt)
{
    const int rt = blockIdx.x, ctc = blockIdx.y;
    const int row0 = rt * 64;
    const int isV = (ctc >= 8);
    const float* W = isV ? Wv : Wk;
    const float* bias_p = isV ? bv : bk;
    const int co0 = (ctc & 7) * 64;

    __shared__ unsigned short As[64 * AP];
    __shared__ unsigned short Bs[64 * AP];
    const int t = threadIdx.x;
    const int lane = t & 63, w = t >> 6;
    const int wr = w >> 1, wc = w & 1;
    const int lm = lane & 15, quad = lane >> 4;
    const int chunk = t & 3, srow = t >> 2;   // 0..63

    f32x4 acc[2][2] = {};

    // A-row global source (clamped padded rows)
    const int rflat = row0 + srow;
    const int b_i = rflat / MPAD, m_i = rflat % MPAD;
    const float* terow = te + ((size_t)b_i * MM + min(m_i, MM - 1)) * TXT;
    const float* wrow  = W + (size_t)(co0 + srow) * TXT;

    for (int k0 = 0; k0 < TXT; k0 += 32) {
        {
            const float4 f0 = *(const float4*)&terow[k0 + chunk * 8];
            const float4 f1 = *(const float4*)&terow[k0 + chunk * 8 + 4];
            us8 o;
            o[0] = f2bf(f0.x); o[1] = f2bf(f0.y); o[2] = f2bf(f0.z); o[3] = f2bf(f0.w);
            o[4] = f2bf(f1.x); o[5] = f2bf(f1.y); o[6] = f2bf(f1.z); o[7] = f2bf(f1.w);
            *(us8*)&As[srow * AP + chunk * 8] = o;

            const float4 g0 = *(const float4*)&wrow[k0 + chunk * 8];
            const float4 g1 = *(const float4*)&wrow[k0 + chunk * 8 + 4];
            us8 ob;
            ob[0] = f2bf(g0.x); ob[1] = f2bf(g0.y); ob[2] = f2bf(g0.z); ob[3] = f2bf(g0.w);
            ob[4] = f2bf(g1.x); ob[5] = f2bf(g1.y); ob[6] = f2bf(g1.z); ob[7] = f2bf(g1.w);
            *(us8*)&Bs[srow * AP + chunk * 8] = ob;
        }
        __syncthreads();
        bf16x8 a[2], bfr[2];
        #pragma unroll
        for (int i = 0; i < 2; ++i)
            a[i] = *(const bf16x8*)&As[(wr * 32 + i * 16 + lm) * AP + quad * 8];
        #pragma unroll
        for (int i = 0; i < 2; ++i)
            bfr[i] = *(const bf16x8*)&Bs[(wc * 32 + i * 16 + lm) * AP + quad * 8];
        #pragma unroll
        for (int mi = 0; mi < 2; ++mi)
            #pragma unroll
            for (int ni = 0; ni < 2; ++ni)
                acc[mi][ni] = __builtin_amdgcn_mfma_f32_16x16x32_bf16(
                    a[mi], bfr[ni], acc[mi][ni], 0, 0, 0);
        __syncthreads();
    }

    #pragma unroll
    for (int ni = 0; ni < 2; ++ni) {
        const int col = co0 + wc * 32 + ni * 16 + lm;
        const float bias = bias_p[col];
        #pragma unroll
        for (int mi = 0; mi < 2; ++mi) {
            #pragma unroll
            for (int j = 0; j < 2 * 2; ++j) {
                const int row = row0 + wr * 32 + mi * 16 + quad * 4 + j;
                const int bo = row / MPAD, mo = row % MPAD;
                const unsigned short hv = f2bf(acc[mi][ni][j] + bias);
                if (isV) {
                    Vt[((size_t)bo * CC + col) * MPAD + mo] = hv;
                } else if (mo < MM) {
                    Kb[((size_t)bo * MM + mo) * CC + col] = hv;
                }
            }
        }
    }
}

// ---------------------------------------------------------------------------
// MFMA attention: block = (128 Q rows, head h, batch b). QK^T via mfma,
// softmax in C-layout regs, exp(P)->LDS (A-layout bf16), PV via mfma,
// epilogue transposed through LDS -> coalesced float4 stores along n.
// ---------------------------------------------------------------------------
__global__ __launch_bounds__(256) void attn_mfma(
    const unsigned short* __restrict__ Qb, const unsigned short* __restrict__ Kb,
    const unsigned short* __restrict__ Vt, const int* __restrict__ amask,
    float* __restrict__ out)
{
    const int ntile = blockIdx.x;   // 0..7
    const int h     = blockIdx.y;   // 0..7
    const int b     = blockIdx.z;   // 0..31
    const int row0  = ntile * 128;

    // union buffer: Ps (128*PP shorts = 26.6KB) then Os (64*OSP floats = 33.8KB)
    __shared__ char smem[64 * OSP * 4];
    __shared__ float msk[80];
    unsigned short* Ps = (unsigned short*)smem;
    float* Os = (float*)smem;

    const int t = threadIdx.x;
    const int w = t >> 6, lane = t & 63;
    const int lm = lane & 15, quad = lane >> 4;

    // zero-fill Ps[:, 80..96) so PV's pad-K reads are clean
    {
        const int r = t >> 1, off = 80 + (t & 1) * 8;
        us8 z = {0, 0, 0, 0, 0, 0, 0, 0};
        *(us8*)&Ps[r * PP + off] = z;
    }
    if (t < 80) msk[t] = (t < MM && amask[b * MM + t] != 0) ? 0.f : -INFINITY;
    __syncthreads();

    // ---- Phase 1: scores = Q K^T (global frag loads) ----
    f32x4 s[2][5] = {};
    const unsigned short* qbase = Qb + ((size_t)b * HWN + row0) * CC + h * HD;
    const unsigned short* kbase = Kb + (size_t)b * MM * CC + h * HD;
    #pragma unroll
    for (int ks = 0; ks < 2; ++ks) {
        bf16x8 a[2], kf[5];
        #pragma unroll
        for (int mt = 0; mt < 2; ++mt)
            a[mt] = *(const bf16x8*)&qbase[(size_t)((w * 2 + mt) * 16 + lm) * CC + ks * 32 + quad * 8];
        #pragma unroll
        for (int n = 0; n < 5; ++n) {
            const int kr = min(n * 16 + lm, MM - 1);
            kf[n] = *(const bf16x8*)&kbase[(size_t)kr * CC + ks * 32 + quad * 8];
        }
        #pragma unroll
        for (int mt = 0; mt < 2; ++mt)
            #pragma unroll
            for (int n = 0; n < 5; ++n)
                s[mt][n] = __builtin_amdgcn_mfma_f32_16x16x32_bf16(a[mt], kf[n], s[mt][n], 0, 0, 0);
    }

    // ---- Phase 2: masked softmax per row ----
    float inv[2][4];
    #pragma unroll
    for (int mt = 0; mt < 2; ++mt) {
        #pragma unroll
        for (int j = 0; j < 4; ++j) {
            float v[5];
            #pragma unroll
            for (int n = 0; n < 5; ++n)
                v[n] = s[mt][n][j] * SCALEF + msk[n * 16 + lm];
            float mx = fmaxf(fmaxf(fmaxf(v[0], v[1]), fmaxf(v[2], v[3])), v[4]);
            mx = fmaxf(mx, __shfl_xor(mx, 1, 64));
            mx = fmaxf(mx, __shfl_xor(mx, 2, 64));
            mx = fmaxf(mx, __shfl_xor(mx, 4, 64));
            mx = fmaxf(mx, __shfl_xor(mx, 8, 64));
            float sum = 0.f;
            #pragma unroll
            for (int n = 0; n < 5; ++n) { v[n] = __expf(v[n] - mx); sum += v[n]; }
            sum += __shfl_xor(sum, 1, 64);
            sum += __shfl_xor(sum, 2, 64);
            sum += __shfl_xor(sum, 4, 64);
            sum += __shfl_xor(sum, 8, 64);
            inv[mt][j] = 1.0f / sum;
            const int mrow = (w * 2 + mt) * 16 + quad * 4 + j;
            #pragma unroll
            for (int n = 0; n < 5; ++n)
                Ps[mrow * PP + n * 16 + lm] = f2bf(v[n]);
        }
    }
    __syncthreads();

    // ---- Phase 3: O = P V ----
    f32x4 o[2][4] = {};
    const unsigned short* vbase = Vt + ((size_t)b * CC + h * HD) * MPAD;
    #pragma unroll
    for (int ks = 0; ks < 3; ++ks) {
        bf16x8 a[2], vf[4];
        #pragma unroll
        for (int mt = 0; mt < 2; ++mt)
            a[mt] = *(const bf16x8*)&Ps[((w * 2 + mt) * 16 + lm) * PP + ks * 32 + quad * 8];
        #pragma unroll
        for (int n = 0; n < 4; ++n)
            vf[n] = *(const bf16x8*)&vbase[(size_t)(n * 16 + lm) * MPAD + ks * 32 + quad * 8];
        #pragma unroll
        for (int mt = 0; mt < 2; ++mt)
            #pragma unroll
            for (int n = 0; n < 4; ++n)
                o[mt][n] = __builtin_amdgcn_mfma_f32_16x16x32_bf16(a[mt], vf[n], o[mt][n], 0, 0, 0);
    }
    __syncthreads();   // Ps fully consumed; smem becomes Os

    // ---- Epilogue 1: scaled O -> Os[col][r], float4 LDS writes ----
    #pragma unroll
    for (int mt = 0; mt < 2; ++mt) {
        #pragma unroll
        for (int n = 0; n < 4; ++n) {
            const int col = n * 16 + lm;
            const int r0 = (w * 2 + mt) * 16 + quad * 4;
            float4 st;
            st.x = o[mt][n][0] * inv[mt][0];
            st.y = o[mt][n][1] * inv[mt][1];
            st.z = o[mt][n][2] * inv[mt][2];
            st.w = o[mt][n][3] * inv[mt][3];
            *(float4*)&Os[col * OSP + r0] = st;
        }
    }
    __syncthreads();

    // ---- Epilogue 2: coalesced float4 stores, contiguous in n ----
    float* obase = out + ((size_t)b * CC + h * HD) * HWN + row0;
    #pragma unroll
    for (int p = 0; p < 8; ++p) {
        const int idx = p * 256 + t;
        const int col = idx >> 5;           // 0..63
        const int r4  = idx & 31;           // float4 index within 128 rows
        const float4 v = *(const float4*)&Os[col * OSP + r4 * 4];
        *(float4*)&obase[(size_t)col * HWN + r4 * 4] = v;
    }
}

extern "C" void kernel_launch(void* const* d_in, const int* in_sizes, int n_in,
                              void* d_out, int out_size, void* d_ws, size_t ws_size,
                              hipStream_t stream)
{
    const float* x     = (const float*)d_in[0];
    const float* te    = (const float*)d_in[1];
    const int*   amask = (const int*)d_in[2];
    const float* Wq    = (const float*)d_in[3];
    const float* bq    = (const float*)d_in[4];
    const float* Wk    = (const float*)d_in[5];
    const float* bk    = (const float*)d_in[6];
    const float* Wv    = (const float*)d_in[7];
    const float* bv    = (const float*)d_in[8];
    float* out = (float*)d_out;

    // Workspace (73.3 MB, same as R3):
    unsigned short* xT  = (unsigned short*)d_ws;
    unsigned short* Qb  = xT + (size_t)BB * HWN * CC;
    unsigned short* Kb  = Qb + (size_t)BB * HWN * CC;
    unsigned short* Vt  = Kb + (size_t)BB * MM * CC;
    unsigned short* Wqb = Vt + (size_t)BB * CC * MPAD;

    wcvt_kernel<<<dim3(CC * CC / 4 / 256), 256, 0, stream>>>(Wq, Wqb);
    tcvt_kernel<<<dim3(16, 8, BB), 256, 0, stream>>>(x, xT);
    qgemm_mfma<<<dim3(256, 4), 256, 0, stream>>>(xT, Wqb, bq, Qb);
    kvgemm_mfma<<<dim3(KVROWS / 64, 16), 256, 0, stream>>>(te, Wk, bk, Wv, bv, Kb, Vt);
    attn_mfma<<<dim3(8, NH, BB), 256, 0, stream>>>(Qb, Kb, Vt, amask, out);
}

// Round 5
// 223.843 us; speedup vs baseline: 2.8750x; 1.0420x over previous
//
#include <hip/hip_runtime.h>
#include <math.h>

// Problem constants
#define BB   32
#define CC   512
#define HWN  1024   // H*W
#define MM   77
#define TXT  768
#define NH   8
#define HD   64
#define SCALEF 0.125f   // 1/sqrt(64)
#define MPAD 96          // padded M for PV K-dim (3 x 32)
#define KVROWS (BB*MPAD) // 3072 padded row space for kv gemm
#define PP   104         // Ps pitch in shorts (104*2=208=13*16B, aligned)
#define OSP  132         // Os pitch in floats (multiple of 4 for float4 align)

typedef __attribute__((ext_vector_type(8))) short          bf16x8; // MFMA A/B frag
typedef __attribute__((ext_vector_type(8))) unsigned short us8;
typedef __attribute__((ext_vector_type(4))) float          f32x4;  // MFMA C/D frag

__device__ inline unsigned short f2bf(float f) {
    union { float f; unsigned u; } v; v.f = f;
    unsigned r = v.u + 0x7fff + ((v.u >> 16) & 1);   // RNE
    return (unsigned short)(r >> 16);
}

__device__ inline void gload_lds16(const void* g, void* l) {
    __builtin_amdgcn_global_load_lds(
        (const __attribute__((address_space(1))) void*)g,
        (__attribute__((address_space(3))) void*)l, 16, 0, 0);
}

// ---------------------------------------------------------------------------
// prep: block-id partitioned.
//  bid < 4096 : x[b,c,n] -> xT[b,n,c] bf16 (64x64 LDS transpose tiles)
//  bid >= 4096: flat fp32->bf16 converts of Wq | Wk | Wv | text_emb
// ---------------------------------------------------------------------------
#define TGRID 4096                   // 16 * 8 * 32 transpose blocks
#define CV_WQ 65536                  // 512*512/4 float4s
#define CV_WK 98304                  // 512*768/4
#define CV_WV 98304
#define CV_TE 473088                 // 2464*768/4
#define CVTOT (CV_WQ + CV_WK + CV_WV + CV_TE)   // 735232 = 2872 * 256

__global__ __launch_bounds__(256) void prep_kernel(
    const float* __restrict__ x, const float* __restrict__ te,
    const float* __restrict__ Wq, const float* __restrict__ Wk,
    const float* __restrict__ Wv,
    unsigned short* __restrict__ xT, unsigned short* __restrict__ teb,
    unsigned short* __restrict__ Wqb, unsigned short* __restrict__ Wkb,
    unsigned short* __restrict__ Wvb)
{
    const int bid = blockIdx.x;
    const int t = threadIdx.x;

    if (bid < TGRID) {
        // ---- transpose+convert x ----
        const int nt = bid & 15, ct = (bid >> 4) & 7, b = bid >> 7;
        const int n0 = nt * 64, c0 = ct * 64;
        __shared__ float tile[64][65];
        const float* xb = x + (size_t)b * CC * HWN;
        {
            const int c = t >> 2;
            #pragma unroll
            for (int j = 0; j < 4; ++j) {
                const int f4 = (t & 3) + j * 4;
                const float4 v = *(const float4*)&xb[(size_t)(c0 + c) * HWN + n0 + f4 * 4];
                tile[c][f4 * 4 + 0] = v.x; tile[c][f4 * 4 + 1] = v.y;
                tile[c][f4 * 4 + 2] = v.z; tile[c][f4 * 4 + 3] = v.w;
            }
        }
        __syncthreads();
        unsigned short* xTb = xT + (size_t)b * HWN * CC;
        #pragma unroll
        for (int j = 0; j < 2; ++j) {
            const int n = (t >> 3) + j * 32;
            const int c8 = (t & 7) * 8;
            us8 o;
            #pragma unroll
            for (int i = 0; i < 8; ++i) o[i] = f2bf(tile[c8 + i][n]);
            *(us8*)&xTb[(size_t)(n0 + n) * CC + c0 + c8] = o;
        }
    } else {
        // ---- flat converts ----
        const int idx = (bid - TGRID) * 256 + t;   // float4 index, < CVTOT
        const float* src; unsigned short* dst; int off;
        if (idx < CV_WQ)                    { src = Wq; dst = Wqb; off = idx; }
        else if (idx < CV_WQ + CV_WK)       { src = Wk; dst = Wkb; off = idx - CV_WQ; }
        else if (idx < CV_WQ + CV_WK + CV_WV) { src = Wv; dst = Wvb; off = idx - CV_WQ - CV_WK; }
        else                                { src = te; dst = teb; off = idx - CV_WQ - CV_WK - CV_WV; }
        const float4 v = ((const float4*)src)[off];
        ushort4 o;
        o.x = f2bf(v.x); o.y = f2bf(v.y); o.z = f2bf(v.z); o.w = f2bf(v.w);
        ((ushort4*)dst)[off] = o;
    }
}

// ---------------------------------------------------------------------------
// gemm_all: merged Q-GEMM + K/V-GEMM, 128x128 tiles, BK=32, 16B global_load_lds
// staging, 4 waves (2x2), 4x4 16x16x32 MFMA tiles per wave.
//  bid < 1024          : Q = xT . Wqb^T + bq        -> Qb bf16 [32768][512]
//  bid in [1024, 1216) : K/V = teb . W^T + bias     -> Kb / Vt (transposed)
// ---------------------------------------------------------------------------
__global__ __launch_bounds__(256) void gemm_all(
    const unsigned short* __restrict__ xT, const unsigned short* __restrict__ Wqb,
    const float* __restrict__ bq, unsigned short* __restrict__ Qb,
    const unsigned short* __restrict__ teb,
    const unsigned short* __restrict__ Wkb, const float* __restrict__ bk,
    const unsigned short* __restrict__ Wvb, const float* __restrict__ bv,
    unsigned short* __restrict__ Kb, unsigned short* __restrict__ Vt)
{
    const int bid = blockIdx.x;
    __shared__ unsigned short As[128 * 32];
    __shared__ unsigned short Bs[128 * 32];
    const int t = threadIdx.x;
    const int lane = t & 63, w = t >> 6;
    const int wr = w >> 1, wc = w & 1;
    const int lm = lane & 15, quad = lane >> 4;
    const int lrow = lane >> 2, lk = (lane & 3) * 8;

    const unsigned short *gA0, *gA1, *gB0, *gB1;
    int kIters, mode, row0, co0;

    if (bid < 1024) {
        mode = 0;
        const int rt = bid & 255, ct = bid >> 8;
        row0 = rt * 128; co0 = ct * 128;
        kIters = CC / 32;
        gA0 = xT  + (size_t)(row0 + (w * 2 + 0) * 16 + lrow) * CC + lk;
        gA1 = xT  + (size_t)(row0 + (w * 2 + 1) * 16 + lrow) * CC + lk;
        gB0 = Wqb + (size_t)(co0 + (w * 2 + 0) * 16 + lrow) * CC + lk;
        gB1 = Wqb + (size_t)(co0 + (w * 2 + 1) * 16 + lrow) * CC + lk;
    } else {
        const int id = bid - 1024;          // 0..191
        const int rt = id % 24, cc = id / 24;
        const int isV = (cc >= 4);
        mode = isV ? 2 : 1;
        row0 = rt * 128; co0 = (cc & 3) * 128;
        kIters = TXT / 32;
        const unsigned short* Wb = isV ? Wvb : Wkb;
        const int rp0 = row0 + (w * 2 + 0) * 16 + lrow;
        const int rp1 = row0 + (w * 2 + 1) * 16 + lrow;
        const int b0i = rp0 / MPAD, m0i = min(rp0 % MPAD, MM - 1);
        const int b1i = rp1 / MPAD, m1i = min(rp1 % MPAD, MM - 1);
        gA0 = teb + (size_t)(b0i * MM + m0i) * TXT + lk;
        gA1 = teb + (size_t)(b1i * MM + m1i) * TXT + lk;
        gB0 = Wb + (size_t)(co0 + (w * 2 + 0) * 16 + lrow) * TXT + lk;
        gB1 = Wb + (size_t)(co0 + (w * 2 + 1) * 16 + lrow) * TXT + lk;
    }

    f32x4 acc[4][4] = {};

    for (int k = 0; k < kIters; ++k) {
        gload_lds16(gA0 + k * 32, &As[(w * 2 + 0) * 512]);
        gload_lds16(gA1 + k * 32, &As[(w * 2 + 1) * 512]);
        gload_lds16(gB0 + k * 32, &Bs[(w * 2 + 0) * 512]);
        gload_lds16(gB1 + k * 32, &Bs[(w * 2 + 1) * 512]);
        __syncthreads();
        bf16x8 a[4], bfr[4];
        #pragma unroll
        for (int i = 0; i < 4; ++i)
            a[i] = *(const bf16x8*)&As[(wr * 64 + i * 16 + lm) * 32 + quad * 8];
        #pragma unroll
        for (int i = 0; i < 4; ++i)
            bfr[i] = *(const bf16x8*)&Bs[(wc * 64 + i * 16 + lm) * 32 + quad * 8];
        #pragma unroll
        for (int mi = 0; mi < 4; ++mi)
            #pragma unroll
            for (int ni = 0; ni < 4; ++ni)
                acc[mi][ni] = __builtin_amdgcn_mfma_f32_16x16x32_bf16(
                    a[mi], bfr[ni], acc[mi][ni], 0, 0, 0);
        __syncthreads();
    }

    if (mode == 0) {
        #pragma unroll
        for (int ni = 0; ni < 4; ++ni) {
            const int col = co0 + wc * 64 + ni * 16 + lm;
            const float bias = bq[col];
            #pragma unroll
            for (int mi = 0; mi < 4; ++mi) {
                #pragma unroll
                for (int j = 0; j < 4; ++j) {
                    const int row = row0 + wr * 64 + mi * 16 + quad * 4 + j;
                    Qb[(size_t)row * CC + col] = f2bf(acc[mi][ni][j] + bias);
                }
            }
        }
    } else {
        const float* bias_p = (mode == 2) ? bv : bk;
        #pragma unroll
        for (int ni = 0; ni < 4; ++ni) {
            const int col = co0 + wc * 64 + ni * 16 + lm;
            const float bias = bias_p[col];
            #pragma unroll
            for (int mi = 0; mi < 4; ++mi) {
                #pragma unroll
                for (int j = 0; j < 4; ++j) {
                    const int row = row0 + wr * 64 + mi * 16 + quad * 4 + j;
                    const int bo = row / MPAD, mo = row % MPAD;
                    const unsigned short hv = f2bf(acc[mi][ni][j] + bias);
                    if (mode == 2) {
                        Vt[((size_t)bo * CC + col) * MPAD + mo] = hv;
                    } else if (mo < MM) {
                        Kb[((size_t)bo * MM + mo) * CC + col] = hv;
                    }
                }
            }
        }
    }
}

// ---------------------------------------------------------------------------
// MFMA attention: block = (128 Q rows, head h, batch b). QK^T via mfma,
// softmax in C-layout regs, exp(P)->LDS (A-layout bf16), PV via mfma,
// epilogue transposed through LDS -> coalesced float4 stores along n.
// ---------------------------------------------------------------------------
__global__ __launch_bounds__(256) void attn_mfma(
    const unsigned short* __restrict__ Qb, const unsigned short* __restrict__ Kb,
    const unsigned short* __restrict__ Vt, const int* __restrict__ amask,
    float* __restrict__ out)
{
    const int ntile = blockIdx.x;   // 0..7
    const int h     = blockIdx.y;   // 0..7
    const int b     = blockIdx.z;   // 0..31
    const int row0  = ntile * 128;

    __shared__ char smem[64 * OSP * 4];   // Ps then Os (unioned)
    __shared__ float msk[80];
    unsigned short* Ps = (unsigned short*)smem;
    float* Os = (float*)smem;

    const int t = threadIdx.x;
    const int w = t >> 6, lane = t & 63;
    const int lm = lane & 15, quad = lane >> 4;

    {
        const int r = t >> 1, off = 80 + (t & 1) * 8;
        us8 z = {0, 0, 0, 0, 0, 0, 0, 0};
        *(us8*)&Ps[r * PP + off] = z;
    }
    if (t < 80) msk[t] = (t < MM && amask[b * MM + t] != 0) ? 0.f : -INFINITY;
    __syncthreads();

    // ---- Phase 1: scores = Q K^T ----
    f32x4 s[2][5] = {};
    const unsigned short* qbase = Qb + ((size_t)b * HWN + row0) * CC + h * HD;
    const unsigned short* kbase = Kb + (size_t)b * MM * CC + h * HD;
    #pragma unroll
    for (int ks = 0; ks < 2; ++ks) {
        bf16x8 a[2], kf[5];
        #pragma unroll
        for (int mt = 0; mt < 2; ++mt)
            a[mt] = *(const bf16x8*)&qbase[(size_t)((w * 2 + mt) * 16 + lm) * CC + ks * 32 + quad * 8];
        #pragma unroll
        for (int n = 0; n < 5; ++n) {
            const int kr = min(n * 16 + lm, MM - 1);
            kf[n] = *(const bf16x8*)&kbase[(size_t)kr * CC + ks * 32 + quad * 8];
        }
        #pragma unroll
        for (int mt = 0; mt < 2; ++mt)
            #pragma unroll
            for (int n = 0; n < 5; ++n)
                s[mt][n] = __builtin_amdgcn_mfma_f32_16x16x32_bf16(a[mt], kf[n], s[mt][n], 0, 0, 0);
    }

    // ---- Phase 2: masked softmax per row ----
    float inv[2][4];
    #pragma unroll
    for (int mt = 0; mt < 2; ++mt) {
        #pragma unroll
        for (int j = 0; j < 4; ++j) {
            float v[5];
            #pragma unroll
            for (int n = 0; n < 5; ++n)
                v[n] = s[mt][n][j] * SCALEF + msk[n * 16 + lm];
            float mx = fmaxf(fmaxf(fmaxf(v[0], v[1]), fmaxf(v[2], v[3])), v[4]);
            mx = fmaxf(mx, __shfl_xor(mx, 1, 64));
            mx = fmaxf(mx, __shfl_xor(mx, 2, 64));
            mx = fmaxf(mx, __shfl_xor(mx, 4, 64));
            mx = fmaxf(mx, __shfl_xor(mx, 8, 64));
            float sum = 0.f;
            #pragma unroll
            for (int n = 0; n < 5; ++n) { v[n] = __expf(v[n] - mx); sum += v[n]; }
            sum += __shfl_xor(sum, 1, 64);
            sum += __shfl_xor(sum, 2, 64);
            sum += __shfl_xor(sum, 4, 64);
            sum += __shfl_xor(sum, 8, 64);
            inv[mt][j] = 1.0f / sum;
            const int mrow = (w * 2 + mt) * 16 + quad * 4 + j;
            #pragma unroll
            for (int n = 0; n < 5; ++n)
                Ps[mrow * PP + n * 16 + lm] = f2bf(v[n]);
        }
    }
    __syncthreads();

    // ---- Phase 3: O = P V ----
    f32x4 o[2][4] = {};
    const unsigned short* vbase = Vt + ((size_t)b * CC + h * HD) * MPAD;
    #pragma unroll
    for (int ks = 0; ks < 3; ++ks) {
        bf16x8 a[2], vf[4];
        #pragma unroll
        for (int mt = 0; mt < 2; ++mt)
            a[mt] = *(const bf16x8*)&Ps[((w * 2 + mt) * 16 + lm) * PP + ks * 32 + quad * 8];
        #pragma unroll
        for (int n = 0; n < 4; ++n)
            vf[n] = *(const bf16x8*)&vbase[(size_t)(n * 16 + lm) * MPAD + ks * 32 + quad * 8];
        #pragma unroll
        for (int mt = 0; mt < 2; ++mt)
            #pragma unroll
            for (int n = 0; n < 4; ++n)
                o[mt][n] = __builtin_amdgcn_mfma_f32_16x16x32_bf16(a[mt], vf[n], o[mt][n], 0, 0, 0);
    }
    __syncthreads();   // Ps fully consumed; smem becomes Os

    // ---- Epilogue 1: scaled O -> Os[col][r], float4 LDS writes ----
    #pragma unroll
    for (int mt = 0; mt < 2; ++mt) {
        #pragma unroll
        for (int n = 0; n < 4; ++n) {
            const int col = n * 16 + lm;
            const int r0 = (w * 2 + mt) * 16 + quad * 4;
            float4 st;
            st.x = o[mt][n][0] * inv[mt][0];
            st.y = o[mt][n][1] * inv[mt][1];
            st.z = o[mt][n][2] * inv[mt][2];
            st.w = o[mt][n][3] * inv[mt][3];
            *(float4*)&Os[col * OSP + r0] = st;
        }
    }
    __syncthreads();

    // ---- Epilogue 2: coalesced float4 stores, contiguous in n ----
    float* obase = out + ((size_t)b * CC + h * HD) * HWN + row0;
    #pragma unroll
    for (int p = 0; p < 8; ++p) {
        const int idx = p * 256 + t;
        const int col = idx >> 5;
        const int r4  = idx & 31;
        const float4 v = *(const float4*)&Os[col * OSP + r4 * 4];
        *(float4*)&obase[(size_t)col * HWN + r4 * 4] = v;
    }
}

extern "C" void kernel_launch(void* const* d_in, const int* in_sizes, int n_in,
                              void* d_out, int out_size, void* d_ws, size_t ws_size,
                              hipStream_t stream)
{
    const float* x     = (const float*)d_in[0];
    const float* te    = (const float*)d_in[1];
    const int*   amask = (const int*)d_in[2];
    const float* Wq    = (const float*)d_in[3];
    const float* bq    = (const float*)d_in[4];
    const float* Wk    = (const float*)d_in[5];
    const float* bk    = (const float*)d_in[6];
    const float* Wv    = (const float*)d_in[7];
    const float* bv    = (const float*)d_in[8];
    float* out = (float*)d_out;

    // Workspace (~78 MB):
    //   xT  bf16 [32][1024][512]   Qb  bf16 [32][1024][512]
    //   Kb  bf16 [32*77][512]      Vt  bf16 [32][512][96]
    //   Wqb [512][512]  Wkb/Wvb [512][768]  teb [2464][768]
    unsigned short* xT  = (unsigned short*)d_ws;
    unsigned short* Qb  = xT  + (size_t)BB * HWN * CC;
    unsigned short* Kb  = Qb  + (size_t)BB * HWN * CC;
    unsigned short* Vt  = Kb  + (size_t)BB * MM * CC;
    unsigned short* Wqb = Vt  + (size_t)BB * CC * MPAD;
    unsigned short* Wkb = Wqb + (size_t)CC * CC;
    unsigned short* Wvb = Wkb + (size_t)CC * TXT;
    unsigned short* teb = Wvb + (size_t)CC * TXT;

    prep_kernel<<<dim3(TGRID + CVTOT / 256), 256, 0, stream>>>(
        x, te, Wq, Wk, Wv, xT, teb, Wqb, Wkb, Wvb);
    gemm_all<<<dim3(1024 + 192), 256, 0, stream>>>(
        xT, Wqb, bq, Qb, teb, Wkb, bk, Wvb, bv, Kb, Vt);
    attn_mfma<<<dim3(8, NH, BB), 256, 0, stream>>>(Qb, Kb, Vt, amask, out);
}